// Round 10
// baseline (220.064 us; speedup 1.0000x reference)
//
#include <hip/hip_runtime.h>
#include <hip/hip_bf16.h>

#define A_N   2048
#define D_N   64
#define FL_N  12
#define KTOT  (A_N * FL_N)          // 24576
#define S_SPLIT 32
#define KCHUNK 768                  // cols per kc-chunk (KTOT/32)
#define NBK   6                     // KCHUNK/128
#define TILE_B 16384                // 64 rows * 128 k * 2B

typedef __attribute__((ext_vector_type(8))) short bf16x8;  // 8 bf16 = 4 VGPRs
typedef __attribute__((ext_vector_type(4))) short bf16x4;  // 8 B
typedef __attribute__((ext_vector_type(4))) float f32x4;

__device__ __forceinline__ short f2bf(float f) {
  union { __hip_bfloat16 b; short s; } u;
  u.b = __float2bfloat16(f);
  return u.s;
}

// ---------- fused setup + conn conversion ----------
// connb2: tile(rt,kc,bk) = contiguous 16 KB = [row r 0..63][k 0..127] bf16 (row-major).
__global__ void k_setup_cvt(const float* __restrict__ pf0, const float* __restrict__ bf0,
                            const float* __restrict__ pf1, const float* __restrict__ bf1,
                            const float* __restrict__ bp, const float* __restrict__ x,
                            const float* __restrict__ conn,
                            short* __restrict__ P2_0, short* __restrict__ P2_1,
                            float* __restrict__ bond0, float* __restrict__ bond1,
                            short* __restrict__ xb, short* __restrict__ connb2) {
  int b = blockIdx.x, t = threadIdx.x;
  if (b >= 768) {
    size_t slot = (size_t)(b - 768) * 256 + t;        // < 1048576
#pragma unroll
    for (int cc = 0; cc < 6; ++cc) {
      size_t i = (slot + (size_t)cc * 1048576) * 8;   // covers 50331648 floats exactly
      f32x4 a0 = __builtin_nontemporal_load((const f32x4*)(conn + i));
      f32x4 a1 = __builtin_nontemporal_load((const f32x4*)(conn + i + 4));
      bf16x8 v;
      v[0]=f2bf(a0[0]); v[1]=f2bf(a0[1]); v[2]=f2bf(a0[2]); v[3]=f2bf(a0[3]);
      v[4]=f2bf(a1[0]); v[5]=f2bf(a1[1]); v[6]=f2bf(a1[2]); v[7]=f2bf(a1[3]);
      int a = (int)(i / KTOT), c = (int)(i % KTOT);   // c is 8-aligned
      int rt = a >> 6, r = a & 63;
      int kc = c / KCHUNK, rem = c - kc * KCHUNK;
      int bk = rem >> 7, k = rem & 127;
      size_t dst = ((size_t)((rt * S_SPLIT + kc) * NBK + bk) << 14) + (r << 8) + (k << 1);
      *(bf16x8*)((char*)connb2 + dst) = v;
    }
    return;
  }
  if (b < 192) {
    int idx = b * 256 + t;                       // < 49152
    int f = (idx >> 6) % FL_N;
    int o = idx / (D_N * FL_N);
    P2_0[idx] = f2bf(pf0[idx] * bf0[(o * FL_N + f) * 3]);
    P2_1[idx] = f2bf(pf1[idx] * bf1[(o * FL_N + f) * 3]);
  } else if (b < 704) {
    int o = t & 63;
    int a = (b - 192) * 4 + (t >> 6);
    float s0 = 0.f, s1 = 0.f;
#pragma unroll
    for (int f = 0; f < FL_N; ++f) {
      float c0 = bp[(a * FL_N + f) * 2 + 0];
      float c1 = bp[(a * FL_N + f) * 2 + 1];
      s0 += c0 * bf0[(o * FL_N + f) * 3 + 1] + c1 * bf0[(o * FL_N + f) * 3 + 2];
      s1 += c0 * bf1[(o * FL_N + f) * 3 + 1] + c1 * bf1[(o * FL_N + f) * 3 + 2];
    }
    bond0[a * D_N + o] = s0;
    bond1[a * D_N + o] = s1;
  } else {
    int i = ((b - 704) * 256 + t) * 8;
    f32x4 a0 = *(const f32x4*)(x + i);
    f32x4 a1 = *(const f32x4*)(x + i + 4);
    bf16x8 v;
    v[0]=f2bf(a0[0]); v[1]=f2bf(a0[1]); v[2]=f2bf(a0[2]); v[3]=f2bf(a0[3]);
    v[4]=f2bf(a1[0]); v[5]=f2bf(a1[1]); v[6]=f2bf(a1[2]); v[7]=f2bf(a1[3]);
    *(bf16x8*)(xb + i) = v;
  }
}

// ---------- Bt prep ----------
// Bt2: slab(kc,bk) = 16 KB FRAGMENT-LINEAR: byte = (j*4+ks)*1024 + lane*16 + kin*2
// where o = j*16 + (lane&15), k = ks*32 + (lane>>4)*8 + kin.
__device__ __forceinline__ void prep_body(bf16x8 h0, bf16x8 h1,
                                          const short* __restrict__ P2,
                                          short* __restrict__ Bt2,
                                          int k0, int lane, int w) {
  int l15 = lane & 15, grp = lane >> 4;
  const short* prow = P2 + (w * 16 + l15) * (FL_N * D_N) + grp * 8;
  f32x4 acc[FL_N];
#pragma unroll
  for (int f = 0; f < FL_N; ++f) {
    bf16x8 p0 = *(const bf16x8*)(prow + f * D_N);
    bf16x8 p1 = *(const bf16x8*)(prow + f * D_N + 32);
    f32x4 c = {0.f, 0.f, 0.f, 0.f};
    c = __builtin_amdgcn_mfma_f32_16x16x32_bf16(p0, h0, c, 0, 0, 0);
    c = __builtin_amdgcn_mfma_f32_16x16x32_bf16(p1, h1, c, 0, 0, 0);
    acc[f] = c;
  }
  // D layout: row(o) = w*16 + grp*4 + r, col(katom) = k0 + l15
#pragma unroll
  for (int r = 0; r < 4; ++r) {
    int o = w * 16 + grp * 4 + r;
    int katom = k0 + l15;
    int j = o >> 4, lo = o & 15;
#pragma unroll
    for (int f = 0; f < FL_N; ++f) {
      int c = katom * FL_N + f;
      int kc = c / KCHUNK;
      int rem = c - kc * KCHUNK;
      int bk = rem >> 7, kk = rem & 127;
      int ks = kk >> 5, g2 = (kk >> 3) & 3, kin = kk & 7;
      *(short*)((char*)Bt2 + (((size_t)(kc * NBK + bk)) << 14)
                + ((j * 4 + ks) << 10) + ((g2 * 16 + lo) << 4) + (kin << 1))
          = f2bf(acc[f][r]);
    }
  }
}

// prep for conv0: h = xb
__global__ void k_prep0(const short* __restrict__ xb, const short* __restrict__ P2,
                        short* __restrict__ Bt2) {
  int lane = threadIdx.x & 63, w = threadIdx.x >> 6;
  int l15 = lane & 15, grp = lane >> 4;
  int k0 = blockIdx.x * 16;
  const short* hrow = xb + (k0 + l15) * D_N + grp * 8;
  bf16x8 h0 = *(const bf16x8*)(hrow);
  bf16x8 h1 = *(const bf16x8*)(hrow + 32);
  prep_body(h0, h1, P2, Bt2, k0, lane, w);
}

// prep conv c>0: reduce prev partials for 16 atoms, bond(+x)+relu, LDS, MFMA-prep.
template <int ADDX>
__global__ void k_prep_r(const float* __restrict__ part, const float* __restrict__ bond,
                         const float* __restrict__ x, const short* __restrict__ P2,
                         short* __restrict__ Bt2) {
  __shared__ short hsh[16 * 64];
  int t = threadIdx.x;
  int k0 = blockIdx.x * 16;
  int r  = t >> 4;            // 0..15 local row
  int d0 = (t & 15) * 4;      // 4 floats per thread
  size_t base = (size_t)(k0 + r) * D_N + d0;
  f32x4 s = *(const f32x4*)(bond + base);
#pragma unroll
  for (int si = 0; si < S_SPLIT; ++si) {
    f32x4 p = *(const f32x4*)(part + (size_t)si * (A_N * D_N) + base);
    s[0] += p[0]; s[1] += p[1]; s[2] += p[2]; s[3] += p[3];
  }
  if (ADDX) {
    f32x4 xv = *(const f32x4*)(x + base);
    s[0] += xv[0]; s[1] += xv[1]; s[2] += xv[2]; s[3] += xv[3];
  }
  bf16x4 hv;
  hv[0] = f2bf(fmaxf(s[0], 0.f)); hv[1] = f2bf(fmaxf(s[1], 0.f));
  hv[2] = f2bf(fmaxf(s[2], 0.f)); hv[3] = f2bf(fmaxf(s[3], 0.f));
  *(bf16x4*)(&hsh[r * 64 + d0]) = hv;
  __syncthreads();
  int lane = t & 63, w = t >> 6, l15 = lane & 15, grp = lane >> 4;
  bf16x8 h0 = *(const bf16x8*)(&hsh[l15 * 64 + grp * 8]);
  bf16x8 h1 = *(const bf16x8*)(&hsh[l15 * 64 + grp * 8 + 32]);
  prep_body(h0, h1, P2, Bt2, k0, lane, w);
}

// ---------- big GEMM: wave-private A staging, B fragment-direct, NO BARRIERS ----------
// Block (rt,kc): 64 rows x 768 k; 6 bk-steps. Wave w owns rows [w*16, w*16+16):
// stages its own 4 KB A quarter into its own LDS region (dbuf, swizzled), reads
// B fragments as contiguous 1 KB wave-loads from L1/L2 (Bt2 is 3 MB, L2-resident).
// grid (32, 32) = 1024 blocks = 4/CU (LDS 32 KB, VGPR<=128) -> 16 waves/CU TLP.
template <int C>
__global__ __launch_bounds__(256, 4) void k_gemm(const short* __restrict__ connb2,
                                                 const short* __restrict__ Bt2,
                                                 float* __restrict__ part) {
  __shared__ short lA[2][8192];   // 16 KB per buf; wave w owns bytes [w*4096, +4096)
  int t = threadIdx.x;
  int lane = t & 63, w = t >> 6, l15 = lane & 15, grp = lane >> 4;
  int rt = blockIdx.x, kc = blockIdx.y;

  const char* Ab = (const char*)connb2
      + (((size_t)(rt * S_SPLIT + kc) * NBK) << 14) + (w << 12);
  const char* Bb = (const char*)Bt2 + (((size_t)kc * NBK) << 14) + (lane << 4);

  // wave-private LDS write offsets (swizzled): chunk j2 = q*64+lane of the 4 KB
  int woff[4];
#pragma unroll
  for (int q = 0; q < 4; ++q) {
    int j2 = q * 64 + lane;
    int row = j2 >> 4, cw = j2 & 15;
    woff[q] = (w << 12) + (row << 8) + ((cw << 4) ^ ((row & 7) << 4));
  }
  // A-fragment read offsets
  int roff[4];
#pragma unroll
  for (int ks = 0; ks < 4; ++ks)
    roff[ks] = (w << 12) + (l15 << 8) + (((ks << 6) + (grp << 4)) ^ ((l15 & 7) << 4));

  bf16x8 ra[4];
#pragma unroll
  for (int q = 0; q < 4; ++q) ra[q] = *(const bf16x8*)(Ab + q * 1024 + (lane << 4));
#pragma unroll
  for (int q = 0; q < 4; ++q) *(bf16x8*)((char*)&lA[0][0] + woff[q]) = ra[q];

  f32x4 acc[4] = {};

#pragma unroll
  for (int bk = 0; bk < NBK; ++bk) {
    const int cur = bk & 1;
    if (bk + 1 < NBK) {                      // issue next A quarter (reg) early
      const char* An = Ab + (size_t)(bk + 1) * TILE_B;
#pragma unroll
      for (int q = 0; q < 4; ++q) ra[q] = *(const bf16x8*)(An + q * 1024 + (lane << 4));
    }
    bf16x8 af[4];
#pragma unroll
    for (int ks = 0; ks < 4; ++ks)
      af[ks] = *(const bf16x8*)((const char*)&lA[cur][0] + roff[ks]);
    const char* Bk = Bb + (size_t)bk * TILE_B;
#pragma unroll
    for (int j = 0; j < 4; ++j) {
      bf16x8 b0 = *(const bf16x8*)(Bk + ((j * 4 + 0) << 10));
      bf16x8 b1 = *(const bf16x8*)(Bk + ((j * 4 + 1) << 10));
      bf16x8 b2 = *(const bf16x8*)(Bk + ((j * 4 + 2) << 10));
      bf16x8 b3 = *(const bf16x8*)(Bk + ((j * 4 + 3) << 10));
      acc[j] = __builtin_amdgcn_mfma_f32_16x16x32_bf16(af[0], b0, acc[j], 0, 0, 0);
      acc[j] = __builtin_amdgcn_mfma_f32_16x16x32_bf16(af[1], b1, acc[j], 0, 0, 0);
      acc[j] = __builtin_amdgcn_mfma_f32_16x16x32_bf16(af[2], b2, acc[j], 0, 0, 0);
      acc[j] = __builtin_amdgcn_mfma_f32_16x16x32_bf16(af[3], b3, acc[j], 0, 0, 0);
    }
    if (bk + 1 < NBK) {                      // write-late into the other buffer
      const int nxt = cur ^ 1;
#pragma unroll
      for (int q = 0; q < 4; ++q) *(bf16x8*)((char*)&lA[nxt][0] + woff[q]) = ra[q];
    }
  }

  float* p = part + (size_t)kc * (A_N * D_N);
  int rbase = rt * 64 + w * 16 + grp * 4;
#pragma unroll
  for (int r = 0; r < 4; ++r) {
    float* pr = p + (size_t)(rbase + r) * D_N + l15;
    pr[0]  = acc[0][r];
    pr[16] = acc[1][r];
    pr[32] = acc[2][r];
    pr[48] = acc[3][r];
  }
}

// ---------- final reduce -> f32 out ----------
__global__ void k_final(const float* __restrict__ part, const float* __restrict__ bond,
                        const float* __restrict__ x, float* __restrict__ out) {
  int i = blockIdx.x * 256 + threadIdx.x;   // 131072 total
  float s = bond[i];
#pragma unroll
  for (int si = 0; si < S_SPLIT; ++si) s += part[(size_t)si * (A_N * D_N) + i];
  out[i] = fmaxf(s + x[i], 0.f);
}

// ---------- launch ----------
extern "C" void kernel_launch(void* const* d_in, const int* in_sizes, int n_in,
                              void* d_out, int out_size, void* d_ws, size_t ws_size,
                              hipStream_t stream) {
  const float* x    = (const float*)d_in[0];
  const float* conn = (const float*)d_in[1];
  const float* bprp = (const float*)d_in[2];
  const float* pf0  = (const float*)d_in[3];
  const float* bf0  = (const float*)d_in[4];
  const float* pf1  = (const float*)d_in[5];
  const float* bf1  = (const float*)d_in[6];
  float* out = (float*)d_out;

  char* ws = (char*)d_ws;
  size_t off = 0;
  short* connb2 = (short*)(ws + off); off += (size_t)A_N * KTOT * 2;           // 100.7 MB
  short* Bt2    = (short*)(ws + off); off += (size_t)D_N * KTOT * 2;           // 3 MB
  float* part   = (float*)(ws + off); off += (size_t)S_SPLIT * A_N * D_N * 4;  // 16.8 MB
  short* xb     = (short*)(ws + off); off += (size_t)A_N * D_N * 2;
  float* bond0  = (float*)(ws + off); off += (size_t)A_N * D_N * 4;
  float* bond1  = (float*)(ws + off); off += (size_t)A_N * D_N * 4;
  short* P2_0   = (short*)(ws + off); off += (size_t)D_N * FL_N * D_N * 2;
  short* P2_1   = (short*)(ws + off); off += (size_t)D_N * FL_N * D_N * 2;

  k_setup_cvt<<<4864, 256, 0, stream>>>(pf0, bf0, pf1, bf1, bprp, x, conn,
                                        P2_0, P2_1, bond0, bond1, xb, connb2);

  dim3 ggrid(32, S_SPLIT);

  // conv0: h = x
  k_prep0<<<128, 256, 0, stream>>>(xb, P2_0, Bt2);
  k_gemm<0><<<ggrid, 256, 0, stream>>>(connb2, Bt2, part);

  // conv1: h1 = relu(conv0); bond0; P2_0
  k_prep_r<0><<<128, 256, 0, stream>>>(part, bond0, x, P2_0, Bt2);
  k_gemm<1><<<ggrid, 256, 0, stream>>>(connb2, Bt2, part);

  // conv2: h2 = relu(conv1 + x); bond0; P2_1
  k_prep_r<1><<<128, 256, 0, stream>>>(part, bond0, x, P2_1, Bt2);
  k_gemm<2><<<ggrid, 256, 0, stream>>>(connb2, Bt2, part);

  // conv3: h3 = relu(conv2); bond1; P2_1
  k_prep_r<0><<<128, 256, 0, stream>>>(part, bond1, x, P2_1, Bt2);
  k_gemm<3><<<ggrid, 256, 0, stream>>>(connb2, Bt2, part);

  // out = relu(conv3 + bond1 + x)
  k_final<<<512, 256, 0, stream>>>(part, bond1, x, out);
}

// Round 11
// 185.826 us; speedup vs baseline: 1.1842x; 1.1842x over previous
//
#include <hip/hip_runtime.h>
#include <hip/hip_bf16.h>

#define A_N   2048
#define D_N   64
#define FL_N  12
#define KTOT  (A_N * FL_N)          // 24576
#define S_SPLIT 16
#define KCHUNK 1536                 // cols per kc-chunk (KTOT/16)
#define NBK   12                    // KCHUNK/128
#define TILE_B 16384                // 64 rows * 128 k * 2B

typedef __attribute__((ext_vector_type(8))) short bf16x8;  // 8 bf16 = 4 VGPRs
typedef __attribute__((ext_vector_type(4))) short bf16x4;  // 8 B
typedef __attribute__((ext_vector_type(4))) float f32x4;

__device__ __forceinline__ short f2bf(float f) {
  union { __hip_bfloat16 b; short s; } u;
  u.b = __float2bfloat16(f);
  return u.s;
}

// async global->LDS, 16 B per lane; lds base must be wave-uniform
__device__ __forceinline__ void gload16(const void* g, void* l) {
  __builtin_amdgcn_global_load_lds(
      (const __attribute__((address_space(1))) unsigned int*)g,
      (__attribute__((address_space(3))) unsigned int*)l, 16, 0, 0);
}

// ---------- fused setup + conn conversion (tiled + SOURCE-SWIZZLED layout) ----------
// connb2: tile(rt,kc,bk) = 16 KB; within tile, logical (row r, chunk cw of 16B)
// stored at physical chunk cw ^ (r&7)  (so linear LDS copy + swizzled ds_read works).
__global__ void k_setup_cvt(const float* __restrict__ pf0, const float* __restrict__ bf0,
                            const float* __restrict__ pf1, const float* __restrict__ bf1,
                            const float* __restrict__ bp, const float* __restrict__ x,
                            const float* __restrict__ conn,
                            short* __restrict__ P2_0, short* __restrict__ P2_1,
                            float* __restrict__ bond0, float* __restrict__ bond1,
                            short* __restrict__ xb, short* __restrict__ connb2) {
  int b = blockIdx.x, t = threadIdx.x;
  if (b >= 768) {
    size_t slot = (size_t)(b - 768) * 256 + t;        // < 1048576
#pragma unroll
    for (int cc = 0; cc < 6; ++cc) {
      size_t i = (slot + (size_t)cc * 1048576) * 8;   // covers 50331648 floats exactly
      f32x4 a0 = __builtin_nontemporal_load((const f32x4*)(conn + i));
      f32x4 a1 = __builtin_nontemporal_load((const f32x4*)(conn + i + 4));
      bf16x8 v;
      v[0]=f2bf(a0[0]); v[1]=f2bf(a0[1]); v[2]=f2bf(a0[2]); v[3]=f2bf(a0[3]);
      v[4]=f2bf(a1[0]); v[5]=f2bf(a1[1]); v[6]=f2bf(a1[2]); v[7]=f2bf(a1[3]);
      int a = (int)(i / KTOT), c = (int)(i % KTOT);   // c is 8-aligned
      int rt = a >> 6, r = a & 63;
      int kc = c / KCHUNK, rem = c % KCHUNK;
      int bk = rem >> 7, k = rem & 127;
      int cw = ((k >> 3) ^ (r & 7));                  // source-side swizzle
      size_t dst = ((size_t)((rt * 16 + kc) * NBK + bk) << 14) + (r << 8) + (cw << 4);
      *(bf16x8*)((char*)connb2 + dst) = v;
    }
    return;
  }
  if (b < 192) {
    int idx = b * 256 + t;                       // < 49152
    int f = (idx >> 6) % FL_N;
    int o = idx / (D_N * FL_N);
    P2_0[idx] = f2bf(pf0[idx] * bf0[(o * FL_N + f) * 3]);
    P2_1[idx] = f2bf(pf1[idx] * bf1[(o * FL_N + f) * 3]);
  } else if (b < 704) {
    int o = t & 63;
    int a = (b - 192) * 4 + (t >> 6);
    float s0 = 0.f, s1 = 0.f;
#pragma unroll
    for (int f = 0; f < FL_N; ++f) {
      float c0 = bp[(a * FL_N + f) * 2 + 0];
      float c1 = bp[(a * FL_N + f) * 2 + 1];
      s0 += c0 * bf0[(o * FL_N + f) * 3 + 1] + c1 * bf0[(o * FL_N + f) * 3 + 2];
      s1 += c0 * bf1[(o * FL_N + f) * 3 + 1] + c1 * bf1[(o * FL_N + f) * 3 + 2];
    }
    bond0[a * D_N + o] = s0;
    bond1[a * D_N + o] = s1;
  } else {
    int i = ((b - 704) * 256 + t) * 8;
    f32x4 a0 = *(const f32x4*)(x + i);
    f32x4 a1 = *(const f32x4*)(x + i + 4);
    bf16x8 v;
    v[0]=f2bf(a0[0]); v[1]=f2bf(a0[1]); v[2]=f2bf(a0[2]); v[3]=f2bf(a0[3]);
    v[4]=f2bf(a1[0]); v[5]=f2bf(a1[1]); v[6]=f2bf(a1[2]); v[7]=f2bf(a1[3]);
    *(bf16x8*)(xb + i) = v;
  }
}

// ---------- Bt prep ----------
// Bt2: slab(kc,bk) = 16 KB, rows are o; same source-side swizzle: chunk (kk>>3)^(o&7).
__device__ __forceinline__ void prep_body(bf16x8 h0, bf16x8 h1,
                                          const short* __restrict__ P2,
                                          short* __restrict__ Bt2,
                                          int k0, int lane, int w) {
  int l15 = lane & 15, grp = lane >> 4;
  const short* prow = P2 + (w * 16 + l15) * (FL_N * D_N) + grp * 8;
  f32x4 acc[FL_N];
#pragma unroll
  for (int f = 0; f < FL_N; ++f) {
    bf16x8 p0 = *(const bf16x8*)(prow + f * D_N);
    bf16x8 p1 = *(const bf16x8*)(prow + f * D_N + 32);
    f32x4 c = {0.f, 0.f, 0.f, 0.f};
    c = __builtin_amdgcn_mfma_f32_16x16x32_bf16(p0, h0, c, 0, 0, 0);
    c = __builtin_amdgcn_mfma_f32_16x16x32_bf16(p1, h1, c, 0, 0, 0);
    acc[f] = c;
  }
  // D layout: row(o) = grp*4 + r (+w*16), col(katom) = l15 (+k0)
#pragma unroll
  for (int r = 0; r < 4; ++r) {
    int o = w * 16 + grp * 4 + r;
    int katom = k0 + l15;
#pragma unroll
    for (int f = 0; f < FL_N; ++f) {
      int c = katom * FL_N + f;
      int kc = c / KCHUNK, rem = c % KCHUNK;
      int bk = rem >> 7, kk = rem & 127;
      int cw = ((kk >> 3) ^ (o & 7));
      *(short*)((char*)Bt2 + ((size_t)(kc * NBK + bk) << 14)
                + (o << 8) + (cw << 4) + ((kk & 7) << 1))
          = f2bf(acc[f][r]);
    }
  }
}

// prep for conv0: h = xb
__global__ void k_prep0(const short* __restrict__ xb, const short* __restrict__ P2,
                        short* __restrict__ Bt2) {
  int lane = threadIdx.x & 63, w = threadIdx.x >> 6;
  int l15 = lane & 15, grp = lane >> 4;
  int k0 = blockIdx.x * 16;
  const short* hrow = xb + (k0 + l15) * D_N + grp * 8;
  bf16x8 h0 = *(const bf16x8*)(hrow);
  bf16x8 h1 = *(const bf16x8*)(hrow + 32);
  prep_body(h0, h1, P2, Bt2, k0, lane, w);
}

// prep conv c>0: reduce prev partials for 16 atoms, bond(+x)+relu, LDS, MFMA-prep.
template <int ADDX>
__global__ void k_prep_r(const float* __restrict__ part, const float* __restrict__ bond,
                         const float* __restrict__ x, const short* __restrict__ P2,
                         short* __restrict__ Bt2) {
  __shared__ short hsh[16 * 64];
  int t = threadIdx.x;
  int k0 = blockIdx.x * 16;
  int r  = t >> 4;            // 0..15 local row
  int d0 = (t & 15) * 4;      // 4 floats per thread
  size_t base = (size_t)(k0 + r) * D_N + d0;
  f32x4 s = *(const f32x4*)(bond + base);
#pragma unroll
  for (int si = 0; si < S_SPLIT; ++si) {
    f32x4 p = *(const f32x4*)(part + (size_t)si * (A_N * D_N) + base);
    s[0] += p[0]; s[1] += p[1]; s[2] += p[2]; s[3] += p[3];
  }
  if (ADDX) {
    f32x4 xv = *(const f32x4*)(x + base);
    s[0] += xv[0]; s[1] += xv[1]; s[2] += xv[2]; s[3] += xv[3];
  }
  bf16x4 hv;
  hv[0] = f2bf(fmaxf(s[0], 0.f)); hv[1] = f2bf(fmaxf(s[1], 0.f));
  hv[2] = f2bf(fmaxf(s[2], 0.f)); hv[3] = f2bf(fmaxf(s[3], 0.f));
  *(bf16x4*)(&hsh[r * 64 + d0]) = hv;
  __syncthreads();
  int lane = t & 63, w = t >> 6, l15 = lane & 15, grp = lane >> 4;
  bf16x8 h0 = *(const bf16x8*)(&hsh[l15 * 64 + grp * 8]);
  bf16x8 h1 = *(const bf16x8*)(&hsh[l15 * 64 + grp * 8 + 32]);
  prep_body(h0, h1, P2, Bt2, k0, lane, w);
}

// ---------- big GEMM: async global_load_lds staging (width 16), swizzled reads ----------
// Block (rt,kc): 64 rows x 1536 k; 12 bk-steps of 64x128 A-tile + 64x128 Bt-slab.
// Stage(bk+1) issued BEFORE compute(bk); single __syncthreads per bk drains DMA.
// grid (32,16) = 512 blocks = 2/CU (LDS 64 KB).
template <int C>
__global__ __launch_bounds__(256, 2) void k_gemm(const short* __restrict__ connb2,
                                                 const short* __restrict__ Bt2,
                                                 float* __restrict__ part) {
  __shared__ short lA[2][8192];   // 16 KB each buf (linear copy of pre-swizzled tile)
  __shared__ short lB[2][8192];
  int t = threadIdx.x;
  int lane = t & 63, w = t >> 6, l15 = lane & 15, grp = lane >> 4;
  int rt = blockIdx.x, kc = blockIdx.y;

  const char* Ab = (const char*)connb2 + (((size_t)(rt * 16 + kc) * NBK) << 14);
  const char* Bb = (const char*)Bt2 + (((size_t)kc * NBK) << 14);
  const int wq = w << 10;          // wave's 1 KB sub-block within each 4 KB quarter
  const int lane16 = lane << 4;

  // prologue: stage tile 0 into buf 0
#pragma unroll
  for (int q = 0; q < 4; ++q) {
    gload16(Ab + q * 4096 + wq + lane16, (char*)&lA[0][0] + q * 4096 + wq);
    gload16(Bb + q * 4096 + wq + lane16, (char*)&lB[0][0] + q * 4096 + wq);
  }
  __syncthreads();

  f32x4 acc0 = {0,0,0,0}, acc1 = {0,0,0,0}, acc2 = {0,0,0,0}, acc3 = {0,0,0,0};
  const int arow = (w * 16 + l15) << 8;     // A row byte base
  const int brow = l15 << 8;                // B row byte base (within o-tile)
  const int key  = (l15 & 7) << 4;

#pragma unroll
  for (int bk = 0; bk < NBK; ++bk) {
    const int cur = bk & 1;
    const int nxt = cur ^ 1;
    if (bk + 1 < NBK) {                     // async-stage tile bk+1 (issue early)
      const char* An = Ab + (size_t)(bk + 1) * TILE_B;
      const char* Bn = Bb + (size_t)(bk + 1) * TILE_B;
#pragma unroll
      for (int q = 0; q < 4; ++q) {
        gload16(An + q * 4096 + wq + lane16, (char*)&lA[nxt][0] + q * 4096 + wq);
        gload16(Bn + q * 4096 + wq + lane16, (char*)&lB[nxt][0] + q * 4096 + wq);
      }
    }
    const char* la = (const char*)&lA[cur][0];
    const char* lb = (const char*)&lB[cur][0];
#pragma unroll
    for (int ks = 0; ks < 4; ++ks) {
      const int cb = ((ks << 6) + (grp << 4)) ^ key;
      bf16x8 af = *(const bf16x8*)(la + arow + cb);
      bf16x8 b0 = *(const bf16x8*)(lb + brow + cb);
      bf16x8 b1 = *(const bf16x8*)(lb + 4096 + brow + cb);
      bf16x8 b2 = *(const bf16x8*)(lb + 8192 + brow + cb);
      bf16x8 b3 = *(const bf16x8*)(lb + 12288 + brow + cb);
      acc0 = __builtin_amdgcn_mfma_f32_16x16x32_bf16(af, b0, acc0, 0, 0, 0);
      acc1 = __builtin_amdgcn_mfma_f32_16x16x32_bf16(af, b1, acc1, 0, 0, 0);
      acc2 = __builtin_amdgcn_mfma_f32_16x16x32_bf16(af, b2, acc2, 0, 0, 0);
      acc3 = __builtin_amdgcn_mfma_f32_16x16x32_bf16(af, b3, acc3, 0, 0, 0);
    }
    if (bk + 1 < NBK) __syncthreads();      // drains DMA for buf[nxt] + protects cur
  }

  float* p = part + (size_t)kc * (A_N * D_N);
  int rbase = rt * 64 + w * 16 + grp * 4;
#pragma unroll
  for (int r = 0; r < 4; ++r) {
    float* pr = p + (size_t)(rbase + r) * D_N + l15;
    pr[0]  = acc0[r];
    pr[16] = acc1[r];
    pr[32] = acc2[r];
    pr[48] = acc3[r];
  }
}

// ---------- final reduce -> f32 out ----------
__global__ void k_final(const float* __restrict__ part, const float* __restrict__ bond,
                        const float* __restrict__ x, float* __restrict__ out) {
  int i = blockIdx.x * 256 + threadIdx.x;   // 131072 total
  float s = bond[i];
#pragma unroll
  for (int si = 0; si < S_SPLIT; ++si) s += part[(size_t)si * (A_N * D_N) + i];
  out[i] = fmaxf(s + x[i], 0.f);
}

// ---------- launch ----------
extern "C" void kernel_launch(void* const* d_in, const int* in_sizes, int n_in,
                              void* d_out, int out_size, void* d_ws, size_t ws_size,
                              hipStream_t stream) {
  const float* x    = (const float*)d_in[0];
  const float* conn = (const float*)d_in[1];
  const float* bprp = (const float*)d_in[2];
  const float* pf0  = (const float*)d_in[3];
  const float* bf0  = (const float*)d_in[4];
  const float* pf1  = (const float*)d_in[5];
  const float* bf1  = (const float*)d_in[6];
  float* out = (float*)d_out;

  char* ws = (char*)d_ws;
  size_t off = 0;
  short* connb2 = (short*)(ws + off); off += (size_t)A_N * KTOT * 2;           // 100.7 MB
  short* Bt2    = (short*)(ws + off); off += (size_t)D_N * KTOT * 2;           // 3 MB
  float* part   = (float*)(ws + off); off += (size_t)S_SPLIT * A_N * D_N * 4;  // 8.4 MB
  short* xb     = (short*)(ws + off); off += (size_t)A_N * D_N * 2;
  float* bond0  = (float*)(ws + off); off += (size_t)A_N * D_N * 4;
  float* bond1  = (float*)(ws + off); off += (size_t)A_N * D_N * 4;
  short* P2_0   = (short*)(ws + off); off += (size_t)D_N * FL_N * D_N * 2;
  short* P2_1   = (short*)(ws + off); off += (size_t)D_N * FL_N * D_N * 2;

  k_setup_cvt<<<4864, 256, 0, stream>>>(pf0, bf0, pf1, bf1, bprp, x, conn,
                                        P2_0, P2_1, bond0, bond1, xb, connb2);

  dim3 ggrid(32, S_SPLIT);

  // conv0: h = x
  k_prep0<<<128, 256, 0, stream>>>(xb, P2_0, Bt2);
  k_gemm<0><<<ggrid, 256, 0, stream>>>(connb2, Bt2, part);

  // conv1: h1 = relu(conv0); bond0; P2_0
  k_prep_r<0><<<128, 256, 0, stream>>>(part, bond0, x, P2_0, Bt2);
  k_gemm<1><<<ggrid, 256, 0, stream>>>(connb2, Bt2, part);

  // conv2: h2 = relu(conv1 + x); bond0; P2_1
  k_prep_r<1><<<128, 256, 0, stream>>>(part, bond0, x, P2_1, Bt2);
  k_gemm<2><<<ggrid, 256, 0, stream>>>(connb2, Bt2, part);

  // conv3: h3 = relu(conv2); bond1; P2_1
  k_prep_r<0><<<128, 256, 0, stream>>>(part, bond1, x, P2_1, Bt2);
  k_gemm<3><<<ggrid, 256, 0, stream>>>(connb2, Bt2, part);

  // out = relu(conv3 + bond1 + x)
  k_final<<<512, 256, 0, stream>>>(part, bond1, x, out);
}